// Round 5
// baseline (1097.608 us; speedup 1.0000x reference)
//
#include <hip/hip_runtime.h>
#include <hip/hip_bf16.h>
#include <math.h>

#define NN 50000
#define DD 128
#define LLAYERS 3
#define RR 16
#define EE 1600000

typedef unsigned int u32;

__device__ __forceinline__ float bflo(u32 u){ union{u32 i;float f;}a; a.i=u<<16; return a.f; }
__device__ __forceinline__ float bfhi(u32 u){ union{u32 i;float f;}a; a.i=u&0xffff0000u; return a.f; }
__device__ __forceinline__ u32 pack_bf2(float x, float y){
  union{float f;u32 i;}a,b; a.f=x; b.f=y;
  u32 xr = (a.i + 0x7fffu + ((a.i>>16)&1u)) >> 16;
  u32 yr = (b.i + 0x7fffu + ((b.i>>16)&1u)) & 0xffff0000u;
  return (xr & 0xffffu) | yr;
}

// ---------------- CSR build (rows padded to multiple of 8 edges) ----------------
__global__ __launch_bounds__(256) void k_hist(const int* __restrict__ rows, int* __restrict__ cnt){
  int e = blockIdx.x*256 + threadIdx.x;
  if (e < EE) atomicAdd(&cnt[rows[e]], 1);
}

__global__ __launch_bounds__(256) void k_scanA(const int* __restrict__ cnt, int* __restrict__ bsum){
  __shared__ int s[256];
  int i = blockIdx.x*256 + threadIdx.x;
  int v = (i < NN) ? ((cnt[i]+7)&~7) : 0;   // padded counts
  s[threadIdx.x] = v; __syncthreads();
  for (int off=128; off>0; off>>=1){
    if (threadIdx.x < off) s[threadIdx.x] += s[threadIdx.x+off];
    __syncthreads();
  }
  if (threadIdx.x==0) bsum[blockIdx.x] = s[0];
}

__global__ __launch_bounds__(256) void k_scanB(int* bsum){
  __shared__ int s[256];
  int t = threadIdx.x;
  int v = bsum[t];
  s[t] = v; __syncthreads();
  for (int off=1; off<256; off<<=1){
    int x = (t>=off) ? s[t-off] : 0; __syncthreads();
    s[t] += x; __syncthreads();
  }
  bsum[t] = s[t] - v; // exclusive block offsets
}

// scanC + pad-fill fused: computes row_ptr/cursor AND zeroes the pad slots
__global__ __launch_bounds__(256) void k_scanC(const int* __restrict__ cnt, const int* __restrict__ bsum,
                        int* __restrict__ row_ptr, int* __restrict__ cursor,
                        int2* __restrict__ colval){
  __shared__ int s[256];
  int t = threadIdx.x; int i = blockIdx.x*256 + t;
  int n = (i<NN)?cnt[i]:0;
  int v = (n+7)&~7;                          // padded count
  s[t]=v; __syncthreads();
  for (int off=1; off<256; off<<=1){
    int x=(t>=off)?s[t-off]:0; __syncthreads();
    s[t]+=x; __syncthreads();
  }
  if (i<NN){
    int e = bsum[blockIdx.x] + s[t]-v;
    row_ptr[i]=e; cursor[i]=e;
    int2 z0; z0.x=0; z0.y=0;
    for (int p=e+n; p<e+v; ++p) colval[p] = z0;     // pad this row
    if (i == NN-1){                                  // tail pad (harmless safety margin)
      for (int p=e+v; p<e+v+128; ++p) colval[p] = z0;
    }
  }
}

// pack (col, val) into one 8B scattered store
__global__ __launch_bounds__(256) void k_scatter(const int* __restrict__ rows, const int* __restrict__ cols,
                          const float* __restrict__ vals,
                          int* __restrict__ cursor, int2* __restrict__ colval){
  int e = blockIdx.x*256+threadIdx.x;
  if (e<EE){
    int r = rows[e];
    int p = atomicAdd(&cursor[r],1);
    int2 cv; cv.x = cols[e]; cv.y = __float_as_int(vals[e]);
    colval[p] = cv;
  }
}

// ---------------- init: h -> bf16 packed + z column sums + gnn_W transpose ----------------
__global__ __launch_bounds__(256) void k_initwT(const float4* __restrict__ nf, uint2* __restrict__ hbf,
                                                float* __restrict__ z,
                                                const float* __restrict__ W, float* __restrict__ wT){
  __shared__ float zp[128];
  int t = threadIdx.x;
  if (t < 128) zp[t] = 0.f;
  // fold gnn_W transpose into the first 192 blocks (one elem per thread)
  if (blockIdx.x < 192){
    int idx = blockIdx.x*256+t; // 49152
    int l = idx >> 14; int r = idx & 16383; int k = r >> 7; int j = r & 127;
    wT[(l<<14) + k*128 + j] = W[(l<<14) + j*128 + k];
  }
  float a0=0.f,a1=0.f,a2=0.f,a3=0.f;
  for (int i = blockIdx.x*256 + t; i < NN*DD/4; i += gridDim.x*256){
    float4 v = nf[i];
    uint2 p; p.x = pack_bf2(v.x, v.y); p.y = pack_bf2(v.z, v.w);
    hbf[i] = p;
    a0 += v.x; a1 += v.y; a2 += v.z; a3 += v.w;
  }
  __syncthreads();
  int c = (t*4) & 127;
  atomicAdd(&zp[c],a0); atomicAdd(&zp[c+1],a1); atomicAdd(&zp[c+2],a2); atomicAdd(&zp[c+3],a3);
  __syncthreads();
  if (t < 128) atomicAdd(&z[((blockIdx.x&15)<<7) + t], zp[t]);
}

#define FMA4(v, h)                                         \
  a0 = fmaf(v, bflo(h.x), a0); a1 = fmaf(v, bfhi(h.x), a1);\
  a2 = fmaf(v, bflo(h.y), a2); a3 = fmaf(v, bfhi(h.y), a3);

// ---------------- fused layer: SPMM (16-row tile -> LDS) + GEMM + ELU + z colsum + bf16 out ----------
// Register-slim SPMM: 32 lanes per edge x uint2 (8B/lane), 2-edge unroll, no deep pipeline.
// __launch_bounds__(256,8) forces <=64 VGPR -> 8 blocks/CU (32 waves/CU) for gather TLP.
// w_s staged in 8KB chunks so LDS (16.6KB) doesn't cap below the VGPR tier.
__global__ __launch_bounds__(256, 8) void k_layer(const int* __restrict__ row_ptr, const int* __restrict__ cnt,
                       const int2* __restrict__ colval,
                       const u32* __restrict__ hin, const float* __restrict__ wTl,
                       const float* __restrict__ bl,
                       u32* __restrict__ hout, float* __restrict__ z, int last){
  __shared__ float a_s[16*128];   // 8 KB
  __shared__ float w_s[16*128];   // 8 KB staging for one wT chunk (16 k-slices)
  __shared__ float zp[128];
  int t = threadIdx.x;
  if (t < 128) zp[t] = 0.f;
  int i0 = blockIdx.x * 16;
  int lane = t & 63;
  int wv = t >> 6;                    // wave id 0..3
  int sub = lane >> 5, q = lane & 31; // half-wave: 32 lanes x 8B = one 128-feat bf16 row

  for (int r = 0; r < 4; ++r){
    int row = i0 + wv*4 + r;
    int base = row_ptr[row], n = cnt[row];
    int iters = ((n + 7) & ~7) >> 2;            // padded count / 4 edges per iter
    const int2* cvp = colval + base + sub;
    float a0=0,a1=0,a2=0,a3=0;
    for (int it = 0; it < iters; ++it){
      int2 cv0 = cvp[0];
      int2 cv1 = cvp[2];
      uint2 h0 = *(const uint2*)&hin[((size_t)(u32)cv0.x<<6) + (q<<1)];
      uint2 h1 = *(const uint2*)&hin[((size_t)(u32)cv1.x<<6) + (q<<1)];
      float v0 = __int_as_float(cv0.y);
      float v1 = __int_as_float(cv1.y);
      FMA4(v0, h0);
      FMA4(v1, h1);
      cvp += 4;
    }
    a0 += __shfl_xor(a0,32);
    a1 += __shfl_xor(a1,32);
    a2 += __shfl_xor(a2,32);
    a3 += __shfl_xor(a3,32);
    if (sub==0){
      float4 o; o.x=a0; o.y=a1; o.z=a2; o.w=a3;
      *(float4*)&a_s[(wv*4+r)*128 + q*4] = o;
    }
  }
  __syncthreads();

  // ---- GEMM phase: thread owns 2 cols x 4 rows; wT staged through LDS in 8 chunks of 16 k
  int jj = lane*2;
  float b0 = bl[jj], b1 = bl[jj+1];
  float acc[4][2];
  #pragma unroll
  for (int r=0;r<4;r++){ acc[r][0]=b0; acc[r][1]=b1; }
  for (int ch=0; ch<8; ++ch){
    const float4* wsrc = (const float4*)(wTl + ch*16*128);
    float4* wdst = (float4*)w_s;
    wdst[t]     = wsrc[t];
    wdst[t+256] = wsrc[t+256];
    __syncthreads();
    #pragma unroll 4
    for (int kk=0;kk<16;kk++){
      float2 w2 = *(const float2*)&w_s[kk*128 + jj];
      int kg = ch*16 + kk;
      #pragma unroll
      for (int r=0;r<4;r++){
        float a = a_s[(wv*4+r)*128 + kg];
        acc[r][0] = fmaf(a, w2.x, acc[r][0]);
        acc[r][1] = fmaf(a, w2.y, acc[r][1]);
      }
    }
    __syncthreads();
  }
  float zc0 = 0.f, zc1 = 0.f;
  #pragma unroll
  for (int r=0;r<4;r++){
    int row = i0 + wv*4 + r;
    float e0 = acc[r][0] > 0.f ? acc[r][0] : expm1f(acc[r][0]);
    float e1 = acc[r][1] > 0.f ? acc[r][1] : expm1f(acc[r][1]);
    zc0 += e0; zc1 += e1;
    if (!last)
      hout[(size_t)row*64 + (jj>>1)] = pack_bf2(e0, e1);
  }
  atomicAdd(&zp[jj], zc0); atomicAdd(&zp[jj+1], zc1);
  __syncthreads();
  if (t < 128) atomicAdd(&z[((blockIdx.x&15)<<7) + t], zp[t]);
}

// hz (redundant per block) + wcol fused. Block 0 also publishes hz to global for k_wrowfinal.
__global__ __launch_bounds__(256) void k_hzwcol(const float* __restrict__ z, const float* __restrict__ fc1W,
                     const float* __restrict__ fc1b, float* __restrict__ hzg,
                     const float* __restrict__ Wc, const float* __restrict__ bc,
                     float* __restrict__ wcol){
  __shared__ float zs[128];
  __shared__ float hzs[128];
  int t = threadIdx.x;
  if (t < 128){
    float s = 0.f;
    #pragma unroll
    for (int q=0;q<16;q++) s += z[(q<<7) + t];
    zs[t] = s * (1.0f / (4.0f * (float)NN));
  }
  __syncthreads();
  if (t < 128){
    float acc = fc1b[t];
    const float* wr = &fc1W[t*128];
    #pragma unroll 8
    for (int k=0;k<128;k++)
      acc = fmaf(zs[k], wr[k], acc);
    float h = acc >= 0.f ? acc : 0.2f*acc;
    hzs[t] = h;
    if (blockIdx.x==0) hzg[t] = h;
  }
  __syncthreads();
  int m = blockIdx.x*256 + t; // < 2048
  float acc = bc[m];
  const float* wr = &Wc[(size_t)m*128];
  #pragma unroll 8
  for (int k=0;k<128;k++)
    acc = fmaf(hzs[k], wr[k], acc);
  wcol[m] = acc;
}

// ---------------- fused wrow+final: one wave per node ----------------
// wave computes wrow[i*16..+15] from fcrow_W (8KB contiguous), then out[i] = ini[i]*(1+wrow·wcol)
__global__ __launch_bounds__(256) void k_wrowfinal(const float* __restrict__ hz, const float* __restrict__ W,
                        const float* __restrict__ b, const float* __restrict__ wcol,
                        const float* __restrict__ ini, float* __restrict__ out){
  __shared__ float wc[16*128];
  int t = threadIdx.x;
  ((float4*)wc)[t] = ((const float4*)wcol)[t];
  ((float4*)wc)[t+256] = ((const float4*)wcol)[t+256];
  __syncthreads();
  int lane = t & 63;
  int i = (blockIdx.x*256 + t) >> 6;   // node id; grid = NN/4 blocks
  int h = lane >> 5;                   // half-wave
  int kq = lane & 31;
  float4 hzv = *(const float4*)&hz[kq*4];
  const float4* wp = (const float4*)(W + (size_t)i*16*128);
  const float* bp = b + (size_t)i*16;
  float wr8[8];
  #pragma unroll
  for (int q=0;q<8;q++){
    // float4 index q*64+lane -> float offset q*256+lane*4 -> row r=2q+h, cols kq*4..+3
    float4 wv = wp[q*64 + lane];
    float p = wv.x*hzv.x;
    p = fmaf(wv.y, hzv.y, p);
    p = fmaf(wv.z, hzv.z, p);
    p = fmaf(wv.w, hzv.w, p);
    p += __shfl_xor(p,1); p += __shfl_xor(p,2); p += __shfl_xor(p,4);
    p += __shfl_xor(p,8); p += __shfl_xor(p,16);
    wr8[q] = p + bp[2*q + h];
  }
  int c = lane*2;
  float a0=0.f, a1=0.f;
  #pragma unroll
  for (int q=0;q<8;q++){
    float we = wr8[q];                    // own r = 2q+h
    float wo = __shfl_xor(wr8[q], 32);    // other half's r = 2q+1-h
    const float2 cA = *(const float2*)&wc[(2*q+h)*128 + c];
    const float2 cB = *(const float2*)&wc[(2*q+1-h)*128 + c];
    a0 = fmaf(we, cA.x, a0); a1 = fmaf(we, cA.y, a1);
    a0 = fmaf(wo, cB.x, a0); a1 = fmaf(wo, cB.y, a1);
  }
  float2 e = *(const float2*)&ini[(size_t)i*128 + c];
  float2 o; o.x = e.x*(1.f+a0); o.y = e.y*(1.f+a1);
  *(float2*)&out[(size_t)i*128 + c] = o;
}

extern "C" void kernel_launch(void* const* d_in, const int* in_sizes, int n_in,
                              void* d_out, int out_size, void* d_ws, size_t ws_size,
                              hipStream_t stream) {
  const int* adj_rows = (const int*)d_in[0];
  const int* adj_cols = (const int*)d_in[1];
  const float* adj_vals = (const float*)d_in[2];
  const float* node_feats = (const float*)d_in[3];
  const float* gnn_W = (const float*)d_in[4];
  const float* gnn_b = (const float*)d_in[5];
  const float* fc1_W = (const float*)d_in[6];
  const float* fc1_b = (const float*)d_in[7];
  const float* fcrow_W = (const float*)d_in[8];
  const float* fcrow_b = (const float*)d_in[9];
  const float* fccol_W = (const float*)d_in[10];
  const float* fccol_b = (const float*)d_in[11];
  const float* ini = (const float*)d_in[12];
  float* out = (float*)d_out;

  char* w = (char*)d_ws;
  auto alloc = [&](size_t bytes)->void*{ void* p = (void*)w; w += (bytes + 255) & ~(size_t)255; return p; };
  // cnt and zb adjacent -> single memset covers both
  int*   cnt    = (int*)  alloc((size_t)NN*4);        // 200000 -> 200192 padded
  float* zb     = (float*)alloc(16*128*4);            // 8192
  u32*   hbf_a  = (u32*)  alloc((size_t)NN*DD*2);
  u32*   hbf_b  = (u32*)  alloc((size_t)NN*DD*2);
  int2*  colval = (int2*) alloc(((size_t)EE + 8*NN + 256)*8);  // padded CSR
  int*   row_ptr= (int*)  alloc((size_t)NN*4);
  int*   cursor = (int*)  alloc((size_t)NN*4);
  int*   bsum   = (int*)  alloc(256*4);
  float* wT     = (float*)alloc(3*128*128*4);
  float* hzb    = (float*)alloc(128*4);
  float* wcolb  = (float*)alloc(2048*4);

  hipMemsetAsync(cnt, 0, ((NN*4 + 255) & ~(size_t)255) + 16*128*4, stream);

  k_hist<<<EE/256, 256, 0, stream>>>(adj_rows, cnt);
  k_scanA<<<256, 256, 0, stream>>>(cnt, bsum);
  k_scanB<<<1, 256, 0, stream>>>(bsum);
  k_scanC<<<256, 256, 0, stream>>>(cnt, bsum, row_ptr, cursor, colval);
  k_scatter<<<EE/256, 256, 0, stream>>>(adj_rows, adj_cols, adj_vals, cursor, colval);
  k_initwT<<<400, 256, 0, stream>>>((const float4*)node_feats, (uint2*)hbf_a, zb, gnn_W, wT);

  const u32* hin = hbf_a; u32* hout = hbf_b;
  for (int l=0; l<LLAYERS; ++l){
    k_layer<<<NN/16, 256, 0, stream>>>(row_ptr, cnt, colval, hin, wT + l*16384,
                                       gnn_b + l*128, hout, zb, (l==LLAYERS-1) ? 1 : 0);
    const u32* tmp = hin; hin = hout; hout = (u32*)tmp;
  }

  k_hzwcol<<<8, 256, 0, stream>>>(zb, fc1_W, fc1_b, hzb, fccol_W, fccol_b, wcolb);
  k_wrowfinal<<<NN/4, 256, 0, stream>>>(hzb, fcrow_W, fcrow_b, wcolb, ini, out);
}